// Round 1
// baseline (1153.179 us; speedup 1.0000x reference)
//
#include <hip/hip_runtime.h>
#include <hip/hip_bf16.h>
#include <math.h>

// Problem constants (match reference setup_inputs)
#define E_TOT   320000
#define NNODE   20000
#define FDIM    128
#define N3F     384
#define NRBF    20
#define OV_SIZE (NNODE * 3 * FDIM)   // out_v elements (first in d_out)

typedef __attribute__((ext_vector_type(8))) short short8;   // 8 bf16 = 4 VGPRs (MFMA A/B frag)
typedef __attribute__((ext_vector_type(4))) short short4v;  // 4 bf16 = 8B
typedef __attribute__((ext_vector_type(4))) float f32x4;    // MFMA C/D frag

// round-to-nearest-even f32 -> bf16 bits
__device__ __forceinline__ short f2bf(float x) {
  union { float f; unsigned u; } v; v.f = x;
  unsigned r = (v.u + 0x7fffu + ((v.u >> 16) & 1u)) >> 16;
  return (short)r;
}

// ---------------- kernel 1: global sum of r^2 (for org_r = r / ||r||_F) ----
__global__ void sumsq_kernel(const float* __restrict__ r, float* __restrict__ ws, int n) {
  int tid = blockIdx.x * blockDim.x + threadIdx.x;
  float acc = 0.f;
  for (int i = tid; i < n; i += gridDim.x * blockDim.x) {
    float x = r[i];
    acc += x * x;
  }
  for (int off = 32; off > 0; off >>= 1) acc += __shfl_down(acc, off);
  __shared__ float s[4];
  int lane = threadIdx.x & 63, w = threadIdx.x >> 6;
  if (lane == 0) s[w] = acc;
  __syncthreads();
  if (threadIdx.x == 0) {
    float t = s[0] + s[1] + s[2] + s[3];
    unsafeAtomicAdd(ws, t);
  }
}

// ---------------- kernel 2: pre-swizzle W_phi / W_w into bf16 MFMA B-fragment order
// B frag for mfma_f32_16x16x32_bf16: lane l holds B[k=(l>>4)*8+j][n=l&15], j=0..7.
// Storage: frag group index g = (fid*64 + lane), 8 contiguous bf16 each.
// fid 0..95  : phi frags, fid = ntile*4 + kstep   (ntile 0..23, kstep 0..3, K=128)
// fid 96..119: w   frags, ntile = fid-96          (single K-step, K=32, rows >=20 zero)
__global__ void prep_kernel(const float* __restrict__ Wphi, const float* __restrict__ Ww,
                            short* __restrict__ frag) {
  int g = blockIdx.x * 256 + threadIdx.x;   // 30 blocks * 256 = 7680 = 120*64
  int lane = g & 63;
  int fid  = g >> 6;
  short* out = frag + (size_t)g * 8;
  if (fid < 96) {
    int ntile = fid >> 2, ks = fid & 3;
    int n  = ntile * 16 + (lane & 15);
    int kb = ks * 32 + (lane >> 4) * 8;
#pragma unroll
    for (int j = 0; j < 8; ++j) out[j] = f2bf(Wphi[(kb + j) * N3F + n]);
  } else if (fid < 120) {
    int ntile = fid - 96;
    int n  = ntile * 16 + (lane & 15);
    int kb = (lane >> 4) * 8;
#pragma unroll
    for (int j = 0; j < 8; ++j) {
      int k = kb + j;
      out[j] = (k < NRBF) ? f2bf(Ww[k * N3F + n]) : (short)0;
    }
  }
}

// ---------------- kernel 3: fused message kernel ---------------------------
// Block = 256 thr (4 waves), 64 edges/block. Wave w owns edges [16w,16w+16).
// Per wave: M=16, N=384 (24 n-tiles as 8 f-tiles x {sp0,sp1,sp2}), K=128 (+32 for w).
__launch_bounds__(256, 2)
__global__ void main_kernel(const float* __restrict__ s_in, const float* __restrict__ r_in,
                            const float* __restrict__ v_in, const int* __restrict__ idx_in,
                            const float* __restrict__ bphi_in, const float* __restrict__ bw_in,
                            const short* __restrict__ frag, const float* __restrict__ ws_sumsq,
                            float* __restrict__ out) {
  // LDS: s tile row stride 136 bf16 (=272B, 16B-aligned, +8 pad kills bank conflicts)
  __shared__ __align__(16) short sh_s[64 * 136];
  __shared__ __align__(16) short sh_rbf[64 * 40];   // 32 K-vals (20 rbf + 12 zero), stride 40
  __shared__ float sh_bphi[N3F];
  __shared__ float sh_bw[N3F];
  __shared__ float sh_orgr[64][4];
  __shared__ int   sh_idx[64];

  const int tid = threadIdx.x;
  const int e0  = blockIdx.x * 64;
  const float inv_gnorm = 1.0f / sqrtf(ws_sumsq[0]);

  // ---- stage s tile (64x128 f32 -> bf16 LDS), coalesced float4 ----
  const float4* s4 = (const float4*)(s_in + (size_t)e0 * FDIM);
#pragma unroll
  for (int it = 0; it < 8; ++it) {
    int idx4 = tid + it * 256;           // 2048 float4 per block
    float4 val = s4[idx4];
    int e = idx4 >> 5, kq = idx4 & 31;
    short4v p = { f2bf(val.x), f2bf(val.y), f2bf(val.z), f2bf(val.w) };
    *(short4v*)&sh_s[e * 136 + kq * 4] = p;
  }
  // ---- biases ----
  for (int j = tid; j < N3F; j += 256) {
    sh_bphi[j] = bphi_in[j];
    sh_bw[j]   = bw_in[j];
  }
  // ---- per-edge: idx, org_r, rbf ----
  if (tid < 64) {
    int e = e0 + tid;
    sh_idx[tid] = idx_in[e];
    float rx = r_in[e * 3 + 0], ry = r_in[e * 3 + 1], rz = r_in[e * 3 + 2];
    float rn = sqrtf(rx * rx + ry * ry + rz * rz);
    float irn = 1.0f / rn;
    sh_orgr[tid][0] = rx * inv_gnorm;
    sh_orgr[tid][1] = ry * inv_gnorm;
    sh_orgr[tid][2] = rz * inv_gnorm;
    const float c0 = 0.62831853071795864769f;  // pi / R_CUT
#pragma unroll
    for (int n = 1; n <= NRBF; ++n) {
      float t = sinf(((float)n * c0) * rn) * irn;
      float val = (t <= 5.0f) ? 0.5f * (cosf(c0 * t) + 1.0f) : 0.0f;
      sh_rbf[tid * 40 + (n - 1)] = f2bf(val);
    }
#pragma unroll
    for (int k = NRBF; k < 32; ++k) sh_rbf[tid * 40 + k] = 0;
  }
  __syncthreads();

  const int wave = tid >> 6, lane = tid & 63;
  const int col  = lane & 15;     // C col within 16-tile; also A-frag row m
  const int q    = lane >> 4;     // quad

  // A fragments (phi: 4 K-steps; w: 1 K-step)
  const int arow = wave * 16 + col;
  short8 a_phi[4];
#pragma unroll
  for (int ks = 0; ks < 4; ++ks)
    a_phi[ks] = *(const short8*)&sh_s[arow * 136 + ks * 32 + q * 8];
  short8 a_w = *(const short8*)&sh_rbf[arow * 40 + q * 8];

  // per-lane epilogue rows: C row = q*4 + i
  int   nidx[4]; int erow[4];
  float orx[4], ory[4], orz[4];
#pragma unroll
  for (int i = 0; i < 4; ++i) {
    int el = wave * 16 + q * 4 + i;
    erow[i] = el;
    nidx[i] = sh_idx[el];
    orx[i] = sh_orgr[el][0];
    ory[i] = sh_orgr[el][1];
    orz[i] = sh_orgr[el][2];
  }

  float* out_v = out;
  float* out_s = out + OV_SIZE;
  const short8* fp = (const short8*)frag;
  const short8* fw = fp + 96 * 64;

  for (int f = 0; f < 8; ++f) {
    const int nt0 = f, nt1 = f + 8, nt2 = f + 16;
    f32x4 accP0 = {0.f, 0.f, 0.f, 0.f}, accP1 = accP0, accP2 = accP0;
    f32x4 accW0 = accP0, accW1 = accP0, accW2 = accP0;
#pragma unroll
    for (int ks = 0; ks < 4; ++ks) {
      short8 b0 = fp[(nt0 * 4 + ks) * 64 + lane];
      short8 b1 = fp[(nt1 * 4 + ks) * 64 + lane];
      short8 b2 = fp[(nt2 * 4 + ks) * 64 + lane];
      accP0 = __builtin_amdgcn_mfma_f32_16x16x32_bf16(a_phi[ks], b0, accP0, 0, 0, 0);
      accP1 = __builtin_amdgcn_mfma_f32_16x16x32_bf16(a_phi[ks], b1, accP1, 0, 0, 0);
      accP2 = __builtin_amdgcn_mfma_f32_16x16x32_bf16(a_phi[ks], b2, accP2, 0, 0, 0);
    }
    accW0 = __builtin_amdgcn_mfma_f32_16x16x32_bf16(a_w, fw[nt0 * 64 + lane], accW0, 0, 0, 0);
    accW1 = __builtin_amdgcn_mfma_f32_16x16x32_bf16(a_w, fw[nt1 * 64 + lane], accW1, 0, 0, 0);
    accW2 = __builtin_amdgcn_mfma_f32_16x16x32_bf16(a_w, fw[nt2 * 64 + lane], accW2, 0, 0, 0);

    const int feat = f * 16 + col;
    const float bp0 = sh_bphi[feat], bp1 = sh_bphi[feat + 128], bp2 = sh_bphi[feat + 256];
    const float bw0 = sh_bw[feat],   bw1 = sh_bw[feat + 128],   bw2 = sh_bw[feat + 256];
#pragma unroll
    for (int i = 0; i < 4; ++i) {
      float sp0 = (accW0[i] + bw0) * (accP0[i] + bp0);
      float sp1 = (accW1[i] + bw1) * (accP1[i] + bp1);
      float sp2 = (accW2[i] + bw2) * (accP2[i] + bp2);
      int node = nidx[i];
      unsafeAtomicAdd(&out_s[node * FDIM + feat], sp1);
      const float* vp = v_in + (size_t)(e0 + erow[i]) * (3 * FDIM) + feat;
      unsafeAtomicAdd(&out_v[(node * 3 + 0) * FDIM + feat], sp2 * orx[i] + sp0 * vp[0]);
      unsafeAtomicAdd(&out_v[(node * 3 + 1) * FDIM + feat], sp2 * ory[i] + sp0 * vp[FDIM]);
      unsafeAtomicAdd(&out_v[(node * 3 + 2) * FDIM + feat], sp2 * orz[i] + sp0 * vp[2 * FDIM]);
    }
  }
}

extern "C" void kernel_launch(void* const* d_in, const int* in_sizes, int n_in,
                              void* d_out, int out_size, void* d_ws, size_t ws_size,
                              hipStream_t stream) {
  const float* s_in  = (const float*)d_in[0];
  const float* r_in  = (const float*)d_in[1];
  const float* v_in  = (const float*)d_in[2];
  const int*   idx_i = (const int*)d_in[3];
  const float* Wphi  = (const float*)d_in[4];
  const float* bphi  = (const float*)d_in[5];
  const float* Ww    = (const float*)d_in[6];
  const float* bw    = (const float*)d_in[7];
  float* out = (float*)d_out;

  // ws layout: [0,16): f32 sumsq accumulator; [16, 16+122880): bf16 W fragments
  float* ws_sumsq = (float*)d_ws;
  short* frag     = (short*)((char*)d_ws + 16);

  hipMemsetAsync(d_out, 0, (size_t)out_size * sizeof(float), stream);
  hipMemsetAsync(d_ws, 0, 16, stream);
  sumsq_kernel<<<480, 256, 0, stream>>>(r_in, ws_sumsq, in_sizes[1]);
  prep_kernel<<<30, 256, 0, stream>>>(Wphi, Ww, frag);
  main_kernel<<<E_TOT / 64, 256, 0, stream>>>(s_in, r_in, v_in, idx_i, bphi, bw,
                                              frag, ws_sumsq, out);
}